// Round 7
// baseline (300.021 us; speedup 1.0000x reference)
//
#include <hip/hip_runtime.h>
#include <hip/hip_bf16.h>

typedef __bf16 bf16x8_t __attribute__((ext_vector_type(8)));
typedef __bf16 bf16x4_t __attribute__((ext_vector_type(4)));
typedef float  f32x4_t  __attribute__((ext_vector_type(4)));

#define MFMA_16x16x32_BF16(A, B, C) __builtin_amdgcn_mfma_f32_16x16x32_bf16((A), (B), (C), 0, 0, 0)

static constexpr int B_ = 16;
static constexpr int T_ = 2048;
static constexpr int C_ = 1024;
static constexpr int H_ = 128;
static constexpr long M_ = (long)B_ * T_;   // 32768 rows

__device__ __forceinline__ void gload_lds16(const void* g, void* l)
{
    __builtin_amdgcn_global_load_lds(
        (const __attribute__((address_space(1))) void*)g,
        (__attribute__((address_space(3))) void*)l, 16, 0, 0);
}

// ---------------------------------------------------------------------------
// W transpose: WT[z][h][c] = bf16(W_z[c][h]).  Flat: WT[n][c], n = z*128+h.
// ---------------------------------------------------------------------------
__global__ __launch_bounds__(128) void wt_kernel(
    const float* __restrict__ Wq, const float* __restrict__ Wk,
    const float* __restrict__ Wv, __bf16* __restrict__ WT)
{
    const int z = blockIdx.y;
    const float* __restrict__ W = (z == 0) ? Wq : (z == 1) ? Wk : Wv;
    const int h  = threadIdx.x;
    const int c0 = blockIdx.x * 8;
    bf16x8_t v;
    #pragma unroll
    for (int j = 0; j < 8; ++j)
        v[j] = (__bf16)W[(c0 + j) * H_ + h];
    *(bf16x8_t*)&WT[((long)z * H_ + h) * C_ + c0] = v;
}

// ---------------------------------------------------------------------------
// Fused projection, v6: m97-faithful. v5 post-mortem: every prior version
// had <=2 blocks/CU (grid- or LDS-capped) -> one barrier domain/CU -> all
// pipes ~25% (latency-bound). m97's 874 TF uses the SAME simple schedule
// but 3+ independent blocks/CU for cross-block overlap (m114).
// Block = 64 rows x 192 cols, 4 waves (2m x 2n), wave = 32x96 = 2 a-frags x
// 6 b-frags = 12 MFMA/k-step. Grid = 512 row-blocks x 2 col-halves = 1024
// blocks = 4 blocks/CU, 16 waves/CU. Double-buffered LDS 40 KB
// (x fp32 8 KB + W 12 KB per buffer) -> exactly 4 blocks/CU.
// T3-minimum schedule (guide 5.5): ISSUE(t+1) BEFORE compute(t), ONE
// __syncthreads per k-step (auto vmcnt/lgkm drain = publication).
// Swizzles both-sides (v3/v5-verified): x unit^=row&7, W unit^=(row>>1)&3.
// Adjacent blockIdx pairs share x rows -> second read L3-hits.
// ---------------------------------------------------------------------------
__global__ __launch_bounds__(256, 4) void proj_kernel(
    const float*  __restrict__ x,
    const __bf16* __restrict__ WT,
    __bf16* __restrict__ qo,
    __bf16* __restrict__ ko,
    __bf16* __restrict__ vo)
{
    __shared__ float  XS[2][64 * 32];    // fp32 x tiles,  8 KB each
    __shared__ __bf16 WS[2][192 * 32];   // bf16 W tiles, 12 KB each

    const int tid  = threadIdx.x;
    const int w    = tid >> 6;
    const int lane = tid & 63;
    const int m16  = lane & 15;
    const int quad = lane >> 4;
    const int wr   = w >> 1;             // row-half 0..1 (32 rows)
    const int wc   = w & 1;              // col-half 0..1 (96 cols)

    const int  rb = blockIdx.x >> 1;     // row-block 0..511
    const int  cb = blockIdx.x & 1;      // col-half  0..1 (pairs share x rows)
    const long r0 = (long)rb * 64;
    const int  n0 = cb * 192;

    // staging lane maps (pre-swizzled GLOBAL source, linear LDS dest)
    const int xl_row = lane >> 3;                      // 0..7 within 8-row chunk
    const int xl_u   = (lane & 7) ^ xl_row;            // f32 4-elem unit
    const int wl_row = lane >> 2;                      // 0..15 within 16-row chunk
    const int wl_u   = (lane & 3) ^ ((lane >> 3) & 3); // bf16 8-elem unit

    f32x4_t acc[2][6];
    #pragma unroll
    for (int hh = 0; hh < 2; ++hh)
        #pragma unroll
        for (int j = 0; j < 6; ++j) acc[hh][j] = f32x4_t{0, 0, 0, 0};

// One k-step's staging: x 2 chunks (8 rows/wave-instr) + W 3 chunks
// (16 rows/wave-instr) = 5 gload_lds16 per thread, 20 KB per block.
#define ISSUE(T, BUF)                                                        \
    {                                                                        \
        const int k0_ = (T) * 32;                                            \
        _Pragma("unroll")                                                    \
        for (int ch = 0; ch < 2; ++ch) {                                     \
            const int rbx = w * 16 + ch * 8;                                 \
            gload_lds16(&x[(r0 + rbx + xl_row) * C_ + k0_ + xl_u * 4],       \
                        &XS[BUF][rbx * 32]);                                 \
        }                                                                    \
        _Pragma("unroll")                                                    \
        for (int ch = 0; ch < 3; ++ch) {                                     \
            const int rbw = w * 48 + ch * 16;                                \
            gload_lds16(&WT[(long)(n0 + rbw + wl_row) * C_ + k0_ + wl_u * 8],\
                        &WS[BUF][rbw * 32]);                                 \
        }                                                                    \
    }

    // ---- prologue: stage k-step 0; publish ----
    ISSUE(0, 0);
    __syncthreads();                     // drains vmcnt -> buf0 ready

    const int asw = m16 & 7;                           // x unit swizzle
    const int qsw = (quad ^ ((m16 >> 1) & 3)) << 3;    // W bf16-elem offset

    for (int t = 0; t < 32; ++t) {
        const int cur = t & 1;
        if (t < 31) ISSUE(t + 1, cur ^ 1);   // staging overlaps this compute

        // a-frags: fp32 -> bf16, swizzled read
        bf16x8_t a[2];
        #pragma unroll
        for (int hh = 0; hh < 2; ++hh) {
            const int row = wr * 32 + hh * 16 + m16;
            f32x4_t lo = *(const f32x4_t*)&XS[cur][row * 32 + (((quad * 2 + 0) ^ asw) << 2)];
            f32x4_t hi = *(const f32x4_t*)&XS[cur][row * 32 + (((quad * 2 + 1) ^ asw) << 2)];
            #pragma unroll
            for (int jj = 0; jj < 4; ++jj) {
                a[hh][jj]     = (__bf16)lo[jj];
                a[hh][4 + jj] = (__bf16)hi[jj];
            }
        }
        // b-frags + 12 MFMAs (b reused x2)
        #pragma unroll
        for (int j = 0; j < 6; ++j) {
            const int row = wc * 96 + j * 16 + m16;
            bf16x8_t b = *(const bf16x8_t*)&WS[cur][row * 32 + qsw];
            #pragma unroll
            for (int hh = 0; hh < 2; ++hh)
                acc[hh][j] = MFMA_16x16x32_BF16(a[hh], b, acc[hh][j]);
        }

        __syncthreads();   // one barrier/step: publishes buf[t+1], frees buf[cur]
    }
#undef ISSUE

    // Epilogue. C/D: col = m16 (n), row = quad*4 + r (m).
    #pragma unroll
    for (int hh = 0; hh < 2; ++hh) {
        const long rbase = r0 + wr * 32 + hh * 16 + quad * 4;
        #pragma unroll
        for (int j = 0; j < 6; ++j) {
            const int nt = cb * 12 + wc * 6 + j;     // 0..23 global n-tile
            const int z  = nt >> 3;
            const int h  = (nt & 7) * 16 + m16;
            if (z < 2) {
                __bf16* __restrict__ o = z ? ko : qo;
                #pragma unroll
                for (int r = 0; r < 4; ++r)
                    o[(rbase + r) * H_ + h] = (__bf16)acc[hh][j][r];
            } else {
                long bb = rbase >> 11, tt = rbase & 2047;  // rows stay in batch
                bf16x4_t pk;
                #pragma unroll
                for (int r = 0; r < 4; ++r) pk[r] = (__bf16)acc[hh][j][r];
                *(bf16x4_t*)&vo[bb * (H_ * (long)T_) + h * (long)T_ + tt] = pk;
            }
        }
    }
}

// ---------------------------------------------------------------------------
// Flash attention, causal, transposed-score, LDS-SHARED K/V tiles.
// (unchanged from the 275 µs baseline)
// ---------------------------------------------------------------------------
__global__ __launch_bounds__(256) void attn_kernel(
    const __bf16* __restrict__ q,   // [B][T][H]
    const __bf16* __restrict__ k,   // [B][T][H]
    const __bf16* __restrict__ vT,  // [B][H][T]
    float* __restrict__ out)        // [B][T][H] fp32
{
    __shared__ __bf16 KS[64 * 136];     // [krow][h], pad 8  (17.4 KB)
    __shared__ __bf16 VS[128 * 72];     // [h][t],    pad 8  (18.4 KB)
    __shared__ __bf16 PS[4][16 * 72];   // per-wave P [q][k], pad 8 (9.2 KB)

    const int L   = blockIdx.x;
    const int b   = L & 15;
    const int Lh  = L >> 4;                       // 0..31
    const int qb  = (Lh < 16) ? (31 - Lh) : (Lh - 16);   // heavy first, CU-paired

    const int tid  = threadIdx.x;
    const int w    = tid >> 6;
    const int lane = tid & 63;
    const int m16  = lane & 15;
    const int quad = lane >> 4;
    const int koff = quad * 8;

    const __bf16* __restrict__ qp = q  + (long)b * T_ * H_;
    const __bf16* __restrict__ kp = k  + (long)b * T_ * H_;
    const __bf16* __restrict__ vp = vT + (long)b * H_ * T_;

    const int q0w = qb * 64 + w * 16;             // wave's q-tile base
    const int qg  = q0w + m16;                    // this lane's q row

    // Q^T B-fragments (lane n=m16=q, k=h)
    bf16x8_t qfr[4];
    #pragma unroll
    for (int s = 0; s < 4; ++s)
        qfr[s] = *(const bf16x8_t*)&qp[(q0w + m16) * H_ + s * 32 + koff];

    f32x4_t acc[8];                               // O^T: row=h, col=q
    #pragma unroll
    for (int i = 0; i < 8; ++i) acc[i] = f32x4_t{0, 0, 0, 0};
    float mrun = -1e30f, lrun = 0.f;

    __bf16* Pb = &PS[w][0];
    const float SC = 0.08838834764831845f;        // 1/sqrt(128)
    const int kend = qb * 64 + 64;

    // staging coords
    const int krow = tid >> 4, kc16 = tid & 15;   // K: 16 thr/row (256B)
    const int vrow = tid >> 3, vc8  = tid & 7;    // V: 8 thr/row (128B)

    for (int tk0 = 0; tk0 < kend; tk0 += 64) {
        __syncthreads();                          // prev compute done
        #pragma unroll
        for (int ch = 0; ch < 4; ++ch) {
            int r = krow + ch * 16;
            *(bf16x8_t*)&KS[r * 136 + kc16 * 8] =
                *(const bf16x8_t*)&kp[(tk0 + r) * H_ + kc16 * 8];
        }
        #pragma unroll
        for (int ch = 0; ch < 4; ++ch) {
            int hh = vrow + ch * 32;
            *(bf16x8_t*)&VS[hh * 72 + vc8 * 8] =
                *(const bf16x8_t*)&vp[hh * (long)T_ + tk0 + vc8 * 8];
        }
        __syncthreads();                          // tiles ready

        // ---- S^T = K Q^T : 4 S-tiles of 16 k-rows ----
        f32x4_t st[4];
        #pragma unroll
        for (int kt = 0; kt < 4; ++kt) {
            f32x4_t s = f32x4_t{0, 0, 0, 0};
            #pragma unroll
            for (int sI = 0; sI < 4; ++sI) {
                bf16x8_t kf = *(const bf16x8_t*)&KS[(kt * 16 + m16) * 136 + sI * 32 + koff];
                s = MFMA_16x16x32_BF16(kf, qfr[sI], s);
            }
            st[kt] = s;
        }

        // ---- scale (+ causal mask only on boundary tiles, wave-uniform) ----
        float vv[4][4];
        if (tk0 + 63 <= q0w) {                    // fully unmasked
            #pragma unroll
            for (int kt = 0; kt < 4; ++kt)
                #pragma unroll
                for (int r = 0; r < 4; ++r)
                    vv[kt][r] = st[kt][r] * SC;
        } else {
            #pragma unroll
            for (int kt = 0; kt < 4; ++kt)
                #pragma unroll
                for (int r = 0; r < 4; ++r) {
                    int kg = tk0 + kt * 16 + quad * 4 + r;
                    vv[kt][r] = (kg <= qg) ? st[kt][r] * SC : -1e30f;
                }
        }

        float mloc = -1e30f;
        #pragma unroll
        for (int kt = 0; kt < 4; ++kt)
            #pragma unroll
            for (int r = 0; r < 4; ++r)
                mloc = fmaxf(mloc, vv[kt][r]);
        mloc = fmaxf(mloc, __shfl_xor(mloc, 16, 64));
        mloc = fmaxf(mloc, __shfl_xor(mloc, 32, 64));

        float mnew = fmaxf(mrun, mloc);
        float al   = __expf(mrun - mnew);
        float psum = 0.f;
        #pragma unroll
        for (int kt = 0; kt < 4; ++kt) {
            bf16x4_t pk;
            #pragma unroll
            for (int r = 0; r < 4; ++r) {
                float p = __expf(vv[kt][r] - mnew);
                psum += p;
                pk[r] = (__bf16)p;
            }
            *(bf16x4_t*)&Pb[m16 * 72 + kt * 16 + quad * 4] = pk;
        }
        psum += __shfl_xor(psum, 16, 64);
        psum += __shfl_xor(psum, 32, 64);
        mrun = mnew;
        lrun = lrun * al + psum;

        #pragma unroll
        for (int i = 0; i < 8; ++i)
            #pragma unroll
            for (int r = 0; r < 4; ++r)
                acc[i][r] *= al;

        // ---- O^T += V^T P^T : two K=32 halves over the 64-wide tile ----
        #pragma unroll
        for (int half = 0; half < 2; ++half) {
            bf16x8_t pa = *(const bf16x8_t*)&Pb[m16 * 72 + half * 32 + koff];
            #pragma unroll
            for (int i = 0; i < 8; ++i) {
                bf16x8_t vf = *(const bf16x8_t*)&VS[(i * 16 + m16) * 72 + half * 32 + koff];
                acc[i] = MFMA_16x16x32_BF16(vf, pa, acc[i]);
            }
        }
    }

    // ---- epilogue: O[q][h] = acc/lrun, f32x4 stores ----
    float* __restrict__ ob = out + (long)b * T_ * H_;
    const float inv = 1.f / lrun;
    #pragma unroll
    for (int i = 0; i < 8; ++i) {
        f32x4_t o;
        #pragma unroll
        for (int r = 0; r < 4; ++r) o[r] = acc[i][r] * inv;
        *(f32x4_t*)&ob[(q0w + m16) * H_ + i * 16 + quad * 4] = o;
    }
}

// ---------------------------------------------------------------------------
extern "C" void kernel_launch(void* const* d_in, const int* in_sizes, int n_in,
                              void* d_out, int out_size, void* d_ws, size_t ws_size,
                              hipStream_t stream)
{
    // setup_inputs order: x, Wk, Wq, Wv — all float32
    const float* x  = (const float*)d_in[0];
    const float* Wk = (const float*)d_in[1];
    const float* Wq = (const float*)d_in[2];
    const float* Wv = (const float*)d_in[3];

    // ws: q [M,H] bf16 | k [M,H] bf16 | vT [B][H][T] bf16 | WT [3][H][C] bf16
    __bf16* qws = (__bf16*)d_ws;
    __bf16* kws = qws + M_ * H_;
    __bf16* vws = kws + M_ * H_;
    __bf16* WT  = vws + (long)B_ * H_ * T_;
    float*  out = (float*)d_out;

    wt_kernel  <<<dim3(C_ / 8, 3), 128, 0, stream>>>(Wq, Wk, Wv, WT);
    proj_kernel<<<dim3((int)(M_ / 64) * 2), 256, 0, stream>>>(x, WT, qws, kws, vws);
    attn_kernel<<<dim3(512), 256, 0, stream>>>(qws, kws, vws, out);
}

// Round 8
// 290.025 us; speedup vs baseline: 1.0345x; 1.0345x over previous
//
#include <hip/hip_runtime.h>
#include <hip/hip_bf16.h>

typedef __bf16 bf16x8_t __attribute__((ext_vector_type(8)));
typedef __bf16 bf16x4_t __attribute__((ext_vector_type(4)));
typedef float  f32x4_t  __attribute__((ext_vector_type(4)));

#define MFMA_16x16x32_BF16(A, B, C) __builtin_amdgcn_mfma_f32_16x16x32_bf16((A), (B), (C), 0, 0, 0)

static constexpr int B_ = 16;
static constexpr int T_ = 2048;
static constexpr int C_ = 1024;
static constexpr int H_ = 128;
static constexpr long M_ = (long)B_ * T_;   // 32768 rows

__device__ __forceinline__ void gload_lds16(const void* g, void* l)
{
    __builtin_amdgcn_global_load_lds(
        (const __attribute__((address_space(1))) void*)g,
        (__attribute__((address_space(3))) void*)l, 16, 0, 0);
}

// ---------------------------------------------------------------------------
// W fragment-linear pack: WB[nt][t][lane][8] bf16, nt=n-tile 0..23 (z=nt>>3,
// within-tile col m16 -> h=(nt&7)*16+m16), t=k-step 0..31, lane=quad*16+m16,
// elems e=0..7 -> W_z[c = t*32+quad*8+e][h].  A wave's MFMA B-fragment for
// (nt,t) is then ONE contiguous 1 KB block: global_load_dwordx4 at
// WB + ((nt*32+t)*64 + lane)*8.  Total 768 KB, L2-resident.
// ---------------------------------------------------------------------------
__global__ __launch_bounds__(256) void wt_kernel(
    const float* __restrict__ Wq, const float* __restrict__ Wk,
    const float* __restrict__ Wv, __bf16* __restrict__ WB)
{
    const int pair = blockIdx.x * 4 + (threadIdx.x >> 6);   // 0..767 = nt*32+t
    const int lane = threadIdx.x & 63;
    const int m16  = lane & 15;
    const int quad = lane >> 4;
    const int nt   = pair >> 5;
    const int t    = pair & 31;
    const int z    = nt >> 3;
    const int h    = (nt & 7) * 16 + m16;
    const float* __restrict__ W = (z == 0) ? Wq : (z == 1) ? Wk : Wv;

    bf16x8_t v;
    #pragma unroll
    for (int e = 0; e < 8; ++e)
        v[e] = (__bf16)W[(t * 32 + quad * 8 + e) * H_ + h];
    *(bf16x8_t*)&WB[((long)pair * 64 + lane) * 8] = v;
}

// ---------------------------------------------------------------------------
// Fused projection, v7: W NEVER touches LDS. v1-v6 post-mortem: all LDS
// variants plateau ~80-100us because the B-operand (768 KB, L2-resident,
// broadcast) is barrier-coupled through LDS every k-step; v4 showed raw
// global frag-gather is TA-bound (16 lines/load). Fix: fragment-linear WB
// (see wt_kernel) -> b-frag = one coalesced 1 KB global load from L2,
// no barrier, no LDS, no swizzle. Only x (4 KB/step) is gload_lds-staged,
// double-buffered, v5-verified XOR swizzle (both-sides). One __syncthreads
// per step; its drain is ~free (MFMA auto-waits retire b + x first).
// Block = 32 rows x 384 cols (grid 1024: x read ONCE), 4 waves, wave =
// 32r x 96c = 2 a-frags x 6 b-frags = 12 MFMA/step. LDS 8 KB -> 4 blk/CU,
// 16 waves/CU, 4 independent barrier domains.
// Floors (overlapped, uncoupled): x-HBM ~11-21us, W-L2 786MB ~23us, MFMA 11us.
// ---------------------------------------------------------------------------
__global__ __launch_bounds__(256, 4) void proj_kernel(
    const float*  __restrict__ x,
    const __bf16* __restrict__ WB,
    __bf16* __restrict__ qo,
    __bf16* __restrict__ ko,
    __bf16* __restrict__ vo)
{
    __shared__ float XS[2][32 * 32];     // fp32 x tiles, 4 KB each

    const int tid  = threadIdx.x;
    const int w    = tid >> 6;
    const int lane = tid & 63;
    const int m16  = lane & 15;
    const int quad = lane >> 4;

    const long r0 = (long)blockIdx.x * 32;

    // x staging lane map (pre-swizzled GLOBAL source, linear LDS dest)
    const int xl_row = lane >> 3;                  // 0..7 within wave's 8 rows
    const int xl_u   = (lane & 7) ^ xl_row;        // f32 4-elem unit

    // wave's b-frag base: n-tiles w*6..w*6+5
    const __bf16* __restrict__ wp = WB + ((long)(w * 6) * 32 + 0) * 512 + lane * 8;

    f32x4_t acc[2][6];
    #pragma unroll
    for (int hh = 0; hh < 2; ++hh)
        #pragma unroll
        for (int j = 0; j < 6; ++j) acc[hh][j] = f32x4_t{0, 0, 0, 0};

#define XSTAGE(T, BUF)                                                       \
    gload_lds16(&x[(r0 + w * 8 + xl_row) * C_ + (T) * 32 + xl_u * 4],        \
                &XS[BUF][w * 8 * 32]);

    // ---- prologue: stage x k-step 0 ----
    XSTAGE(0, 0);
    __syncthreads();

    const int asw = m16 & 7;                       // x unit swizzle (read side)

    for (int t = 0; t < 32; ++t) {
        const int cur = t & 1;
        if (t < 31) XSTAGE(t + 1, cur ^ 1);        // 1 instr/wave, lands under compute

        // b-frags: 6 coalesced 1 KB loads from L2 (fragment-linear WB)
        bf16x8_t b[6];
        #pragma unroll
        for (int j = 0; j < 6; ++j)
            b[j] = *(const bf16x8_t*)(wp + ((long)j * 32 + t) * 512);

        // a-frags: fp32 -> bf16, swizzled LDS read
        bf16x8_t a[2];
        #pragma unroll
        for (int hh = 0; hh < 2; ++hh) {
            const int row = hh * 16 + m16;
            f32x4_t lo = *(const f32x4_t*)&XS[cur][row * 32 + (((quad * 2 + 0) ^ asw) << 2)];
            f32x4_t hi = *(const f32x4_t*)&XS[cur][row * 32 + (((quad * 2 + 1) ^ asw) << 2)];
            #pragma unroll
            for (int jj = 0; jj < 4; ++jj) {
                a[hh][jj]     = (__bf16)lo[jj];
                a[hh][4 + jj] = (__bf16)hi[jj];
            }
        }

        #pragma unroll
        for (int j = 0; j < 6; ++j)
            #pragma unroll
            for (int hh = 0; hh < 2; ++hh)
                acc[hh][j] = MFMA_16x16x32_BF16(a[hh], b[j], acc[hh][j]);

        __syncthreads();   // publishes XS[t+1]; drain ~free (b/x already retired)
    }
#undef XSTAGE

    // Epilogue. C/D: col = m16 (n), row = quad*4 + r (m).
    #pragma unroll
    for (int hh = 0; hh < 2; ++hh) {
        const long rbase = r0 + hh * 16 + quad * 4;
        #pragma unroll
        for (int j = 0; j < 6; ++j) {
            const int nt = w * 6 + j;
            const int z  = nt >> 3;
            const int h  = (nt & 7) * 16 + m16;
            if (z < 2) {
                __bf16* __restrict__ o = z ? ko : qo;
                #pragma unroll
                for (int r = 0; r < 4; ++r)
                    o[(rbase + r) * H_ + h] = (__bf16)acc[hh][j][r];
            } else {
                long bb = rbase >> 11, tt = rbase & 2047;  // 32 | 2048: rows stay in batch
                bf16x4_t pk;
                #pragma unroll
                for (int r = 0; r < 4; ++r) pk[r] = (__bf16)acc[hh][j][r];
                *(bf16x4_t*)&vo[bb * (H_ * (long)T_) + h * (long)T_ + tt] = pk;
            }
        }
    }
}

// ---------------------------------------------------------------------------
// Flash attention, causal, transposed-score, LDS-SHARED K/V tiles.
// (unchanged from the 275 µs baseline)
// ---------------------------------------------------------------------------
__global__ __launch_bounds__(256) void attn_kernel(
    const __bf16* __restrict__ q,   // [B][T][H]
    const __bf16* __restrict__ k,   // [B][T][H]
    const __bf16* __restrict__ vT,  // [B][H][T]
    float* __restrict__ out)        // [B][T][H] fp32
{
    __shared__ __bf16 KS[64 * 136];     // [krow][h], pad 8  (17.4 KB)
    __shared__ __bf16 VS[128 * 72];     // [h][t],    pad 8  (18.4 KB)
    __shared__ __bf16 PS[4][16 * 72];   // per-wave P [q][k], pad 8 (9.2 KB)

    const int L   = blockIdx.x;
    const int b   = L & 15;
    const int Lh  = L >> 4;                       // 0..31
    const int qb  = (Lh < 16) ? (31 - Lh) : (Lh - 16);   // heavy first, CU-paired

    const int tid  = threadIdx.x;
    const int w    = tid >> 6;
    const int lane = tid & 63;
    const int m16  = lane & 15;
    const int quad = lane >> 4;
    const int koff = quad * 8;

    const __bf16* __restrict__ qp = q  + (long)b * T_ * H_;
    const __bf16* __restrict__ kp = k  + (long)b * T_ * H_;
    const __bf16* __restrict__ vp = vT + (long)b * H_ * T_;

    const int q0w = qb * 64 + w * 16;             // wave's q-tile base
    const int qg  = q0w + m16;                    // this lane's q row

    // Q^T B-fragments (lane n=m16=q, k=h)
    bf16x8_t qfr[4];
    #pragma unroll
    for (int s = 0; s < 4; ++s)
        qfr[s] = *(const bf16x8_t*)&qp[(q0w + m16) * H_ + s * 32 + koff];

    f32x4_t acc[8];                               // O^T: row=h, col=q
    #pragma unroll
    for (int i = 0; i < 8; ++i) acc[i] = f32x4_t{0, 0, 0, 0};
    float mrun = -1e30f, lrun = 0.f;

    __bf16* Pb = &PS[w][0];
    const float SC = 0.08838834764831845f;        // 1/sqrt(128)
    const int kend = qb * 64 + 64;

    // staging coords
    const int krow = tid >> 4, kc16 = tid & 15;   // K: 16 thr/row (256B)
    const int vrow = tid >> 3, vc8  = tid & 7;    // V: 8 thr/row (128B)

    for (int tk0 = 0; tk0 < kend; tk0 += 64) {
        __syncthreads();                          // prev compute done
        #pragma unroll
        for (int ch = 0; ch < 4; ++ch) {
            int r = krow + ch * 16;
            *(bf16x8_t*)&KS[r * 136 + kc16 * 8] =
                *(const bf16x8_t*)&kp[(tk0 + r) * H_ + kc16 * 8];
        }
        #pragma unroll
        for (int ch = 0; ch < 4; ++ch) {
            int hh = vrow + ch * 32;
            *(bf16x8_t*)&VS[hh * 72 + vc8 * 8] =
                *(const bf16x8_t*)&vp[hh * (long)T_ + tk0 + vc8 * 8];
        }
        __syncthreads();                          // tiles ready

        // ---- S^T = K Q^T : 4 S-tiles of 16 k-rows ----
        f32x4_t st[4];
        #pragma unroll
        for (int kt = 0; kt < 4; ++kt) {
            f32x4_t s = f32x4_t{0, 0, 0, 0};
            #pragma unroll
            for (int sI = 0; sI < 4; ++sI) {
                bf16x8_t kf = *(const bf16x8_t*)&KS[(kt * 16 + m16) * 136 + sI * 32 + koff];
                s = MFMA_16x16x32_BF16(kf, qfr[sI], s);
            }
            st[kt] = s;
        }

        // ---- scale (+ causal mask only on boundary tiles, wave-uniform) ----
        float vv[4][4];
        if (tk0 + 63 <= q0w) {                    // fully unmasked
            #pragma unroll
            for (int kt = 0; kt < 4; ++kt)
                #pragma unroll
                for (int r = 0; r < 4; ++r)
                    vv[kt][r] = st[kt][r] * SC;
        } else {
            #pragma unroll
            for (int kt = 0; kt < 4; ++kt)
                #pragma unroll
                for (int r = 0; r < 4; ++r) {
                    int kg = tk0 + kt * 16 + quad * 4 + r;
                    vv[kt][r] = (kg <= qg) ? st[kt][r] * SC : -1e30f;
                }
        }

        float mloc = -1e30f;
        #pragma unroll
        for (int kt = 0; kt < 4; ++kt)
            #pragma unroll
            for (int r = 0; r < 4; ++r)
                mloc = fmaxf(mloc, vv[kt][r]);
        mloc = fmaxf(mloc, __shfl_xor(mloc, 16, 64));
        mloc = fmaxf(mloc, __shfl_xor(mloc, 32, 64));

        float mnew = fmaxf(mrun, mloc);
        float al   = __expf(mrun - mnew);
        float psum = 0.f;
        #pragma unroll
        for (int kt = 0; kt < 4; ++kt) {
            bf16x4_t pk;
            #pragma unroll
            for (int r = 0; r < 4; ++r) {
                float p = __expf(vv[kt][r] - mnew);
                psum += p;
                pk[r] = (__bf16)p;
            }
            *(bf16x4_t*)&Pb[m16 * 72 + kt * 16 + quad * 4] = pk;
        }
        psum += __shfl_xor(psum, 16, 64);
        psum += __shfl_xor(psum, 32, 64);
        mrun = mnew;
        lrun = lrun * al + psum;

        #pragma unroll
        for (int i = 0; i < 8; ++i)
            #pragma unroll
            for (int r = 0; r < 4; ++r)
                acc[i][r] *= al;

        // ---- O^T += V^T P^T : two K=32 halves over the 64-wide tile ----
        #pragma unroll
        for (int half = 0; half < 2; ++half) {
            bf16x8_t pa = *(const bf16x8_t*)&Pb[m16 * 72 + half * 32 + koff];
            #pragma unroll
            for (int i = 0; i < 8; ++i) {
                bf16x8_t vf = *(const bf16x8_t*)&VS[(i * 16 + m16) * 72 + half * 32 + koff];
                acc[i] = MFMA_16x16x32_BF16(vf, pa, acc[i]);
            }
        }
    }

    // ---- epilogue: O[q][h] = acc/lrun, f32x4 stores ----
    float* __restrict__ ob = out + (long)b * T_ * H_;
    const float inv = 1.f / lrun;
    #pragma unroll
    for (int i = 0; i < 8; ++i) {
        f32x4_t o;
        #pragma unroll
        for (int r = 0; r < 4; ++r) o[r] = acc[i][r] * inv;
        *(f32x4_t*)&ob[(q0w + m16) * H_ + i * 16 + quad * 4] = o;
    }
}

// ---------------------------------------------------------------------------
extern "C" void kernel_launch(void* const* d_in, const int* in_sizes, int n_in,
                              void* d_out, int out_size, void* d_ws, size_t ws_size,
                              hipStream_t stream)
{
    // setup_inputs order: x, Wk, Wq, Wv — all float32
    const float* x  = (const float*)d_in[0];
    const float* Wk = (const float*)d_in[1];
    const float* Wq = (const float*)d_in[2];
    const float* Wv = (const float*)d_in[3];

    // ws: q [M,H] bf16 | k [M,H] bf16 | vT [B][H][T] bf16 | WB [24][32][64][8] bf16
    __bf16* qws = (__bf16*)d_ws;
    __bf16* kws = qws + M_ * H_;
    __bf16* vws = kws + M_ * H_;
    __bf16* WB  = vws + (long)B_ * H_ * T_;
    float*  out = (float*)d_out;

    wt_kernel  <<<dim3(192), 256, 0, stream>>>(Wq, Wk, Wv, WB);
    proj_kernel<<<dim3((int)(M_ / 32)), 256, 0, stream>>>(x, WB, qws, kws, vws);
    attn_kernel<<<dim3(512), 256, 0, stream>>>(qws, kws, vws, out);
}